// Round 3
// baseline (424.430 us; speedup 1.0000x reference)
//
#include <hip/hip_runtime.h>
#include <hip/hip_bf16.h>

namespace {
constexpr int S  = 4096;
constexpr int D  = 768;
constexpr int H  = 12;
constexpr int N3 = 2304;   // 3*D

typedef __bf16 bf16x4 __attribute__((ext_vector_type(4)));
typedef __bf16 bf16x8 __attribute__((ext_vector_type(8)));
typedef float  floatx4 __attribute__((ext_vector_type(4)));

// async global->LDS, 16B per lane; LDS dest = wave-uniform base + lane*16.
__device__ inline void glds16(const __bf16* g, __bf16* l) {
  __builtin_amdgcn_global_load_lds(
      (const __attribute__((address_space(1))) void*)(const void*)g,
      (__attribute__((address_space(3))) void*)(void*)l, 16, 0, 0);
}

// ---------------------------------------------------------------------------
// Kernel 0: merged converts. bid < 3072: x fp32 -> bf16 (1024 elems/block).
// Else: W [768][2304] fp32 -> WT [2304][768] bf16 via LDS tile transpose.
// ---------------------------------------------------------------------------
__global__ __launch_bounds__(256)
void convert_all(const float* __restrict__ x, __bf16* __restrict__ xb,
                 const float* __restrict__ W, __bf16* __restrict__ WT)
{
  const int bid = blockIdx.x;
  const int tid = threadIdx.x;
  if (bid < 3072) {
    const int i = (bid * 256 + tid) * 4;
    floatx4 v = *reinterpret_cast<const floatx4*>(x + i);
    bf16x4 b;
    #pragma unroll
    for (int e = 0; e < 4; ++e) b[e] = (__bf16)v[e];
    *reinterpret_cast<bf16x4*>(xb + i) = b;
  } else {
    __shared__ float T[64][65];
    const int b2 = bid - 3072;
    const int d0 = (b2 % 12) * 64, e0 = (b2 / 12) * 64;
    const int rr = tid >> 4, c4 = (tid & 15) * 4;
    #pragma unroll
    for (int it = 0; it < 4; ++it) {
      int d = it * 16 + rr;
      floatx4 v = *reinterpret_cast<const floatx4*>(W + (d0 + d) * N3 + e0 + c4);
      #pragma unroll
      for (int e = 0; e < 4; ++e) T[d][c4 + e] = v[e];
    }
    __syncthreads();
    #pragma unroll
    for (int it = 0; it < 4; ++it) {
      int e = it * 16 + rr;
      bf16x4 b;
      #pragma unroll
      for (int i = 0; i < 4; ++i) b[i] = (__bf16)T[c4 + i][e];
      *reinterpret_cast<bf16x4*>(WT + (e0 + e) * D + d0 + c4) = b;
    }
  }
}

// ---------------------------------------------------------------------------
// Kernel 1 (VERBATIM): QKV GEMM, 128x96 tile, grid 32x24 = 768 = 3/CU.
// glds16 + XOR swizzle, BK=64. Q/K direct stores; V via swizzled-LDS
// transpose (k-slot-permuted) then coalesced 16B vT stores.
// ---------------------------------------------------------------------------
__global__ __launch_bounds__(256)
void qkv_gemm(const __bf16* __restrict__ xb, const __bf16* __restrict__ WT,
              const float* __restrict__ bq, __bf16* __restrict__ Qb,
              __bf16* __restrict__ Kb, __bf16* __restrict__ vT)
{
  __shared__ __bf16 smem[14336];           // 28 KB: As(16K) | Bs(12K); vts(24K)
  __bf16* As = smem;                        // [128][64] swizzled
  __bf16* Bs = smem + 8192;                 // [96][64]  swizzled

  const int tid  = threadIdx.x;
  const int wave = tid >> 6, lane = tid & 63;
  const int quad = lane >> 4, l16 = lane & 15;
  const int m_base = (wave >> 1) * 64;
  const int n_base = (wave & 1) * 48;
  const int bm = blockIdx.x, bn = blockIdx.y;
  const int srow = lane >> 3, sg = lane & 7;

  floatx4 acc[4][3];
  #pragma unroll
  for (int i = 0; i < 4; ++i)
    #pragma unroll
    for (int j = 0; j < 3; ++j) acc[i][j] = (floatx4){0.f, 0.f, 0.f, 0.f};

  for (int ks = 0; ks < 12; ++ks) {
    const int k0 = ks * 64;
    __syncthreads();
    #pragma unroll
    for (int it = 0; it < 4; ++it) {
      int rbase = it * 32 + wave * 8;
      int row = rbase + srow;
      glds16(xb + (size_t)(bm * 128 + row) * D + k0 + (sg ^ (row & 7)) * 8,
             As + rbase * 64);
    }
    #pragma unroll
    for (int it = 0; it < 3; ++it) {
      int rbase = it * 32 + wave * 8;
      int row = rbase + srow;
      glds16(WT + (size_t)(bn * 96 + row) * D + k0 + (sg ^ (row & 7)) * 8,
             Bs + rbase * 64);
    }
    __syncthreads();

    bf16x8 af[4][2], bfr[3][2];
    #pragma unroll
    for (int mt = 0; mt < 4; ++mt)
      #pragma unroll
      for (int kt = 0; kt < 2; ++kt) {
        int m = m_base + mt * 16 + l16;
        af[mt][kt] = *reinterpret_cast<const bf16x8*>(
            &As[m * 64 + ((((kt << 2) | quad) ^ (l16 & 7)) << 3)]);
      }
    #pragma unroll
    for (int nt = 0; nt < 3; ++nt)
      #pragma unroll
      for (int kt = 0; kt < 2; ++kt) {
        int n = n_base + nt * 16 + l16;
        bfr[nt][kt] = *reinterpret_cast<const bf16x8*>(
            &Bs[n * 64 + ((((kt << 2) | quad) ^ (l16 & 7)) << 3)]);
      }
    #pragma unroll
    for (int kt = 0; kt < 2; ++kt)
      #pragma unroll
      for (int mt = 0; mt < 4; ++mt)
        #pragma unroll
        for (int nt = 0; nt < 3; ++nt)
          acc[mt][nt] = __builtin_amdgcn_mfma_f32_16x16x32_bf16(
              af[mt][kt], bfr[nt][kt], acc[mt][nt], 0, 0, 0);
  }

  if (bn < 16) {
    #pragma unroll
    for (int nt = 0; nt < 3; ++nt) {
      int col = bn * 96 + n_base + nt * 16 + l16;
      float bias = bq[col];
      #pragma unroll
      for (int mt = 0; mt < 4; ++mt) {
        int row = bm * 128 + m_base + mt * 16 + quad * 4;
        #pragma unroll
        for (int r = 0; r < 4; ++r) {
          __bf16 v = (__bf16)(acc[mt][nt][r] + bias);
          if (bn < 8) Qb[(row + r) * D + col] = v;
          else        Kb[(row + r) * D + (col - D)] = v;
        }
      }
    }
  } else {
    __syncthreads();
    __bf16* vts = smem;   // [w 96][t 128], addr = w*128 + (pos ^ ((w&7)<<3))
    #pragma unroll
    for (int nt = 0; nt < 3; ++nt) {
      int wl = n_base + nt * 16 + l16;
      float bias = bq[bn * 96 + wl];
      int sw = (wl & 7) << 3;
      #pragma unroll
      for (int mt = 0; mt < 4; ++mt) {
        #pragma unroll
        for (int r = 0; r < 4; ++r) {
          int tl = m_base + mt * 16 + quad * 4 + r;
          int pos = (tl & ~31) | (quad << 3) | ((tl & 16) >> 2) | r;
          vts[wl * 128 + (pos ^ sw)] = (__bf16)(acc[mt][nt][r] + bias);
        }
      }
    }
    __syncthreads();
    const int w0g = bn * 96 - 2 * D;
    #pragma unroll
    for (int it = 0; it < 6; ++it) {
      int c = it * 256 + tid;
      int wl = c >> 4, t0 = (c & 15) * 8;
      bf16x8 v = *reinterpret_cast<const bf16x8*>(
          &vts[wl * 128 + (t0 ^ ((wl & 7) << 3))]);
      *reinterpret_cast<bf16x8*>(
          &vT[(size_t)(w0g + wl) * S + bm * 128 + t0]) = v;
    }
  }
}

// ---------------------------------------------------------------------------
// Kernel 2: flash attention, 8-wave (512-thread) blocks for SIMD fill.
//  Same 64q x 128t tile, waves = 2 qh x 4 th (each wave 32q x 32t per step).
//  Grid stays 768 -> 3 blocks/CU -> 24 waves/CU = 6/SIMD (launch_bounds 512,6).
//  Same counted-vmcnt ping-pong pipeline (K dbuf + late V), adapted counts:
//  per wave per iter: K=2, V=2, mask=2 glds/loads.
//    top of iter: outstanding K(j)2 oldest, V(j)2; issue mask 2 -> 6;
//      vmcnt(4) drains K(j).  B1.  stageK(j+1) +2.
//    QK: compiler's mask-use wait = vmcnt(2): drains V(j), leaves K(j+1).
//      explicit vmcnt(2) before B_mid guarantees it.  PV.  B2.  stageV(j+1).
//  P packed DIRECTLY into pf[nt][mt*4+r] (no ps->pf concat). Vt slot for
//  PV = (th*4+quad) ^ (w&7): identical t-permutation algebra as before
//  (e&3=r, e>>2=mt), so the GEMM's vT layout is unchanged.
//  4-way th-reduction via padded LDS partials (stride 33 floats).
//  LDS: Ks0|Ks1 (16K each) + Vt (16K) = 48K staging; reduction aliases
//  50688B partials + 768B Ll = 51456 total -> 3 blocks/CU (151KB/160KB).
// ---------------------------------------------------------------------------
__global__ __launch_bounds__(512, 6)
void attention(const __bf16* __restrict__ Qb, const __bf16* __restrict__ Kb,
               const __bf16* __restrict__ vT, const float* __restrict__ mask,
               float* __restrict__ out)
{
  __shared__ char smem[51456];
  __bf16* Vt = (__bf16*)(smem + 32768);       // [64][128], swizzled+permuted-t

  const int tid  = threadIdx.x;
  const int wave = tid >> 6, lane = tid & 63;
  const int quad = lane >> 4, l16 = lane & 15;
  const int qh = wave >> 2;       // q-half (0..1)
  const int th = wave & 3;        // t-quarter (0..3)
  const int qb = blockIdx.x, h = blockIdx.y;
  const int q0 = qb * 64;
  const int qcol = h * 64;
  const int srow = lane >> 3, sg = lane & 7;
  const int vrow = lane >> 4, vs = lane & 15;

  bf16x8 qf[2][2];
  #pragma unroll
  for (int nt = 0; nt < 2; ++nt)
    #pragma unroll
    for (int kt = 0; kt < 2; ++kt)
      qf[nt][kt] = *reinterpret_cast<const bf16x8*>(
          Qb + (q0 + qh * 32 + nt * 16 + l16) * D + qcol + kt * 32 + quad * 8);

  floatx4 accO[4][2];
  #pragma unroll
  for (int wt = 0; wt < 4; ++wt)
    #pragma unroll
    for (int nt = 0; nt < 2; ++nt) accO[wt][nt] = (floatx4){0.f, 0.f, 0.f, 0.f};
  floatx4 accL[2];
  accL[0] = (floatx4){0.f, 0.f, 0.f, 0.f};
  accL[1] = (floatx4){0.f, 0.f, 0.f, 0.f};
  bf16x8 ones;
  #pragma unroll
  for (int e = 0; e < 8; ++e) ones[e] = (__bf16)1.0f;

  // K tile [128][64]: 512 lanes x 16B = 64 rows/round, 2 rounds.
  auto stageK = [&](int j, __bf16* dst) {
    #pragma unroll
    for (int it = 0; it < 2; ++it) {
      int rbase = it * 64 + wave * 8;
      int t = rbase + srow;
      glds16(Kb + (size_t)(j * 128 + t) * D + qcol + (sg ^ (t & 7)) * 8,
             dst + rbase * 64);
    }
  };
  // V tile [64][128]: 512 lanes x 16B = 32 w-rows/round, 2 rounds.
  auto stageV = [&](int j) {
    #pragma unroll
    for (int it = 0; it < 2; ++it) {
      int wbase = it * 32 + wave * 4;
      int w = wbase + vrow;
      glds16(vT + (size_t)(qcol + w) * S + j * 128 + (vs ^ (w & 7)) * 8,
             Vt + wbase * 128);
    }
  };

  __builtin_amdgcn_sched_barrier(0);
  // prologue: K(0), V(0) in flight
  stageK(0, (__bf16*)smem);
  stageV(0);
  __builtin_amdgcn_sched_barrier(0);

  for (int j = 0; j < 32; ++j) {
    // mask loads for this step (issued before the counted wait)
    floatx4 mv[2];
    #pragma unroll
    for (int mt = 0; mt < 2; ++mt)
      mv[mt] = *reinterpret_cast<const floatx4*>(
          mask + j * 128 + th * 32 + mt * 16 + quad * 4);

    asm volatile("s_waitcnt vmcnt(4)" ::: "memory");   // own K(j) drained
    __builtin_amdgcn_s_barrier();                      // B1: K(j) visible
    __builtin_amdgcn_sched_barrier(0);

    if (j < 31)                                        // prefetch next K
      stageK(j + 1, (__bf16*)(smem + (((j + 1) & 1) << 14)));
    __builtin_amdgcn_sched_barrier(0);

    const __bf16* Kc = (const __bf16*)(smem + ((j & 1) << 14));

    // S^T = K Q^T ; P = exp2(scale*S + mask2) packed directly into pf.
    bf16x8 pf[2];
    #pragma unroll
    for (int mt = 0; mt < 2; ++mt) {
      int trow = th * 32 + mt * 16 + l16;
      bf16x8 kf[2];
      #pragma unroll
      for (int kt = 0; kt < 2; ++kt)
        kf[kt] = *reinterpret_cast<const bf16x8*>(
            &Kc[trow * 64 + ((((kt << 2) | quad) ^ (l16 & 7)) << 3)]);
      floatx4 am;   // (m-1)*10000*log2e ; exactly 0 when m==1
      #pragma unroll
      for (int r = 0; r < 4; ++r)
        am[r] = fmaf(mv[mt][r], 14426.9504f, -14426.9504f);
      #pragma unroll
      for (int nt = 0; nt < 2; ++nt) {
        floatx4 s = (floatx4){0.f, 0.f, 0.f, 0.f};
        #pragma unroll
        for (int kt = 0; kt < 2; ++kt)
          s = __builtin_amdgcn_mfma_f32_16x16x32_bf16(kf[kt], qf[nt][kt], s, 0, 0, 0);
        #pragma unroll
        for (int r = 0; r < 4; ++r)
          pf[nt][mt * 4 + r] = (__bf16)__builtin_amdgcn_exp2f(
              fmaf(s[r], 0.18033688f, am[r]));   // 0.125*log2e
      }
    }

    asm volatile("s_waitcnt vmcnt(2)" ::: "memory");   // V(j) drained; K(j+1) flies
    __builtin_amdgcn_s_barrier();                      // B_mid: V(j) visible
    __builtin_amdgcn_sched_barrier(0);

    // O^T += V^T P^T ; l via ones-MFMA (sums P columns, rows all equal).
    #pragma unroll
    for (int nt = 0; nt < 2; ++nt)
      accL[nt] = __builtin_amdgcn_mfma_f32_16x16x32_bf16(
          ones, pf[nt], accL[nt], 0, 0, 0);
    #pragma unroll
    for (int wt = 0; wt < 4; ++wt) {
      int w = wt * 16 + l16;
      bf16x8 vf = *reinterpret_cast<const bf16x8*>(
          &Vt[w * 128 + (((th * 4 + quad) ^ (w & 7)) << 3)]);
      #pragma unroll
      for (int nt = 0; nt < 2; ++nt)
        accO[wt][nt] = __builtin_amdgcn_mfma_f32_16x16x32_bf16(
            vf, pf[nt], accO[wt][nt], 0, 0, 0);
    }

    __builtin_amdgcn_s_barrier();                      // B2: Vt readers done
    __builtin_amdgcn_sched_barrier(0);
    if (j < 31) stageV(j + 1);                         // prefetch next V
    __builtin_amdgcn_sched_barrier(0);
  }

  // l for q = nt*16+l16 over this wave's 32 t: all 4 acc rows identical.
  float l_lane[2] = {accL[0][0], accL[1][0]};

  // ---- 4-way cross-wave reduction over t-quarters ----
  float* Lo = (float*)smem;              // 6 partials x [64][33] f32 = 50688B
  float* Ll = (float*)(smem + 50688);    // 6 x 32 f32 l partials
  __syncthreads();   // full drain; safe to alias Lo over K/V buffers
  if (th != 0) {
    float* dst = Lo + (qh * 3 + th - 1) * 2112;
    #pragma unroll
    for (int wt = 0; wt < 4; ++wt)
      #pragma unroll
      for (int nt = 0; nt < 2; ++nt)
        #pragma unroll
        for (int r = 0; r < 4; ++r)
          dst[(wt * 16 + quad * 4 + r) * 33 + nt * 16 + l16] = accO[wt][nt][r];
    if (quad == 0) {
      #pragma unroll
      for (int nt = 0; nt < 2; ++nt)
        Ll[(qh * 3 + th - 1) * 32 + nt * 16 + l16] = l_lane[nt];
    }
  }
  __syncthreads();
  if (th == 0) {
    float l_tot[2];
    #pragma unroll
    for (int nt = 0; nt < 2; ++nt) {
      l_tot[nt] = l_lane[nt];
      #pragma unroll
      for (int p = 0; p < 3; ++p)
        l_tot[nt] += Ll[(qh * 3 + p) * 32 + nt * 16 + l16];
    }
    #pragma unroll
    for (int wt = 0; wt < 4; ++wt)
      #pragma unroll
      for (int nt = 0; nt < 2; ++nt) {
        floatx4 o;
        #pragma unroll
        for (int r = 0; r < 4; ++r) {
          float v = accO[wt][nt][r];
          #pragma unroll
          for (int p = 0; p < 3; ++p)
            v += Lo[(qh * 3 + p) * 2112 +
                    (wt * 16 + quad * 4 + r) * 33 + nt * 16 + l16];
          o[r] = v / l_tot[nt];
        }
        int row = q0 + qh * 32 + nt * 16 + l16;
        int col = qcol + wt * 16 + quad * 4;
        *reinterpret_cast<floatx4*>(&out[row * D + col]) = o;
      }
  }
}

} // namespace

extern "C" void kernel_launch(void* const* d_in, const int* in_sizes, int n_in,
                              void* d_out, int out_size, void* d_ws, size_t ws_size,
                              hipStream_t stream) {
  const float *x = nullptr, *mask = nullptr, *Wq = nullptr, *bq = nullptr;
  for (int i = 0; i < n_in; ++i) {
    switch (in_sizes[i]) {
      case 3145728: x    = (const float*)d_in[i]; break;
      case 4096:    mask = (const float*)d_in[i]; break;
      case 1769472: Wq   = (const float*)d_in[i]; break;
      case 2304:    bq   = (const float*)d_in[i]; break;
      default: break;
    }
  }

  __bf16* xb = (__bf16*)d_out;               // bf16 scratch in d_out
  __bf16* WT = xb + (size_t)S * D;
  __bf16* Qb = (__bf16*)d_ws;
  __bf16* Kb = Qb + (size_t)S * D;
  __bf16* vT = Kb + (size_t)S * D;

  convert_all<<<3072 + 432, 256, 0, stream>>>(x, xb, Wq, WT);
  qkv_gemm   <<<dim3(S / 128, N3 / 96), 256, 0, stream>>>(xb, WT, bq, Qb, Kb, vT);
  attention  <<<dim3(S / 64, H), 512, 0, stream>>>(Qb, Kb, vT, mask, (float*)d_out);
}

// Round 4
// 174.507 us; speedup vs baseline: 2.4322x; 2.4322x over previous
//
#include <hip/hip_runtime.h>
#include <hip/hip_bf16.h>

namespace {
constexpr int S  = 4096;
constexpr int D  = 768;
constexpr int H  = 12;
constexpr int N3 = 2304;   // 3*D

typedef __bf16 bf16x4 __attribute__((ext_vector_type(4)));
typedef __bf16 bf16x8 __attribute__((ext_vector_type(8)));
typedef float  floatx4 __attribute__((ext_vector_type(4)));

// async global->LDS, 16B per lane; LDS dest = wave-uniform base + lane*16.
__device__ inline void glds16(const __bf16* g, __bf16* l) {
  __builtin_amdgcn_global_load_lds(
      (const __attribute__((address_space(1))) void*)(const void*)g,
      (__attribute__((address_space(3))) void*)(void*)l, 16, 0, 0);
}

// ---------------------------------------------------------------------------
// Kernel 0: merged converts. bid < 3072: x fp32 -> bf16 (1024 elems/block).
// Else: W [768][2304] fp32 -> WT [2304][768] bf16 via LDS tile transpose.
// ---------------------------------------------------------------------------
__global__ __launch_bounds__(256)
void convert_all(const float* __restrict__ x, __bf16* __restrict__ xb,
                 const float* __restrict__ W, __bf16* __restrict__ WT)
{
  const int bid = blockIdx.x;
  const int tid = threadIdx.x;
  if (bid < 3072) {
    const int i = (bid * 256 + tid) * 4;
    floatx4 v = *reinterpret_cast<const floatx4*>(x + i);
    bf16x4 b;
    #pragma unroll
    for (int e = 0; e < 4; ++e) b[e] = (__bf16)v[e];
    *reinterpret_cast<bf16x4*>(xb + i) = b;
  } else {
    __shared__ float T[64][65];
    const int b2 = bid - 3072;
    const int d0 = (b2 % 12) * 64, e0 = (b2 / 12) * 64;
    const int rr = tid >> 4, c4 = (tid & 15) * 4;
    #pragma unroll
    for (int it = 0; it < 4; ++it) {
      int d = it * 16 + rr;
      floatx4 v = *reinterpret_cast<const floatx4*>(W + (d0 + d) * N3 + e0 + c4);
      #pragma unroll
      for (int e = 0; e < 4; ++e) T[d][c4 + e] = v[e];
    }
    __syncthreads();
    #pragma unroll
    for (int it = 0; it < 4; ++it) {
      int e = it * 16 + rr;
      bf16x4 b;
      #pragma unroll
      for (int i = 0; i < 4; ++i) b[i] = (__bf16)T[c4 + i][e];
      *reinterpret_cast<bf16x4*>(WT + (e0 + e) * D + d0 + c4) = b;
    }
  }
}

// ---------------------------------------------------------------------------
// Kernel 1 (VERBATIM): QKV GEMM, 128x96 tile, grid 32x24 = 768 = 3/CU.
// glds16 + XOR swizzle, BK=64. Q/K direct stores; V via swizzled-LDS
// transpose (k-slot-permuted) then coalesced 16B vT stores.
// ---------------------------------------------------------------------------
__global__ __launch_bounds__(256)
void qkv_gemm(const __bf16* __restrict__ xb, const __bf16* __restrict__ WT,
              const float* __restrict__ bq, __bf16* __restrict__ Qb,
              __bf16* __restrict__ Kb, __bf16* __restrict__ vT)
{
  __shared__ __bf16 smem[14336];           // 28 KB: As(16K) | Bs(12K); vts(24K)
  __bf16* As = smem;                        // [128][64] swizzled
  __bf16* Bs = smem + 8192;                 // [96][64]  swizzled

  const int tid  = threadIdx.x;
  const int wave = tid >> 6, lane = tid & 63;
  const int quad = lane >> 4, l16 = lane & 15;
  const int m_base = (wave >> 1) * 64;
  const int n_base = (wave & 1) * 48;
  const int bm = blockIdx.x, bn = blockIdx.y;
  const int srow = lane >> 3, sg = lane & 7;

  floatx4 acc[4][3];
  #pragma unroll
  for (int i = 0; i < 4; ++i)
    #pragma unroll
    for (int j = 0; j < 3; ++j) acc[i][j] = (floatx4){0.f, 0.f, 0.f, 0.f};

  for (int ks = 0; ks < 12; ++ks) {
    const int k0 = ks * 64;
    __syncthreads();
    #pragma unroll
    for (int it = 0; it < 4; ++it) {
      int rbase = it * 32 + wave * 8;
      int row = rbase + srow;
      glds16(xb + (size_t)(bm * 128 + row) * D + k0 + (sg ^ (row & 7)) * 8,
             As + rbase * 64);
    }
    #pragma unroll
    for (int it = 0; it < 3; ++it) {
      int rbase = it * 32 + wave * 8;
      int row = rbase + srow;
      glds16(WT + (size_t)(bn * 96 + row) * D + k0 + (sg ^ (row & 7)) * 8,
             Bs + rbase * 64);
    }
    __syncthreads();

    bf16x8 af[4][2], bfr[3][2];
    #pragma unroll
    for (int mt = 0; mt < 4; ++mt)
      #pragma unroll
      for (int kt = 0; kt < 2; ++kt) {
        int m = m_base + mt * 16 + l16;
        af[mt][kt] = *reinterpret_cast<const bf16x8*>(
            &As[m * 64 + ((((kt << 2) | quad) ^ (l16 & 7)) << 3)]);
      }
    #pragma unroll
    for (int nt = 0; nt < 3; ++nt)
      #pragma unroll
      for (int kt = 0; kt < 2; ++kt) {
        int n = n_base + nt * 16 + l16;
        bfr[nt][kt] = *reinterpret_cast<const bf16x8*>(
            &Bs[n * 64 + ((((kt << 2) | quad) ^ (l16 & 7)) << 3)]);
      }
    #pragma unroll
    for (int kt = 0; kt < 2; ++kt)
      #pragma unroll
      for (int mt = 0; mt < 4; ++mt)
        #pragma unroll
        for (int nt = 0; nt < 3; ++nt)
          acc[mt][nt] = __builtin_amdgcn_mfma_f32_16x16x32_bf16(
              af[mt][kt], bfr[nt][kt], acc[mt][nt], 0, 0, 0);
  }

  if (bn < 16) {
    #pragma unroll
    for (int nt = 0; nt < 3; ++nt) {
      int col = bn * 96 + n_base + nt * 16 + l16;
      float bias = bq[col];
      #pragma unroll
      for (int mt = 0; mt < 4; ++mt) {
        int row = bm * 128 + m_base + mt * 16 + quad * 4;
        #pragma unroll
        for (int r = 0; r < 4; ++r) {
          __bf16 v = (__bf16)(acc[mt][nt][r] + bias);
          if (bn < 8) Qb[(row + r) * D + col] = v;
          else        Kb[(row + r) * D + (col - D)] = v;
        }
      }
    }
  } else {
    __syncthreads();
    __bf16* vts = smem;   // [w 96][t 128], addr = w*128 + (pos ^ ((w&7)<<3))
    #pragma unroll
    for (int nt = 0; nt < 3; ++nt) {
      int wl = n_base + nt * 16 + l16;
      float bias = bq[bn * 96 + wl];
      int sw = (wl & 7) << 3;
      #pragma unroll
      for (int mt = 0; mt < 4; ++mt) {
        #pragma unroll
        for (int r = 0; r < 4; ++r) {
          int tl = m_base + mt * 16 + quad * 4 + r;
          int pos = (tl & ~31) | (quad << 3) | ((tl & 16) >> 2) | r;
          vts[wl * 128 + (pos ^ sw)] = (__bf16)(acc[mt][nt][r] + bias);
        }
      }
    }
    __syncthreads();
    const int w0g = bn * 96 - 2 * D;
    #pragma unroll
    for (int it = 0; it < 6; ++it) {
      int c = it * 256 + tid;
      int wl = c >> 4, t0 = (c & 15) * 8;
      bf16x8 v = *reinterpret_cast<const bf16x8*>(
          &vts[wl * 128 + (t0 ^ ((wl & 7) << 3))]);
      *reinterpret_cast<bf16x8*>(
          &vT[(size_t)(w0g + wl) * S + bm * 128 + t0]) = v;
    }
  }
}

// ---------------------------------------------------------------------------
// Kernel 2: flash attention, 8-wave (512-thread) blocks.
//  R3 structure UNCHANGED except __launch_bounds__(512, 4): the (512,6)
//  variant imposed an ~85-VGPR budget, spilled the accumulators to scratch
//  (VGPR_Count 40, 1.46 GB HBM traffic/dispatch, 4x slowdown). (512,4)
//  gives a 128-VGPR budget (live state ~100), 2 blocks/CU co-resident:
//  16 waves/CU = 4/SIMD vs R2's 12/CU = 3/SIMD.
//  Counted-vmcnt ping-pong pipeline; per wave per iter: K=2, V=2, mask=2.
//    top of iter: outstanding K(j)2 oldest, V(j)2; issue mask 2 -> 6;
//      vmcnt(4) drains K(j).  B1.  stageK(j+1) +2.
//    QK: explicit vmcnt(2) before B_mid drains V(j), leaves K(j+1).
//    PV.  B2.  stageV(j+1).
//  P packed DIRECTLY into pf[nt][mt*4+r]. Vt slot for PV = (th*4+quad)^(w&7).
//  4-way th-reduction via padded LDS partials (stride 33 floats).
//  LDS: Ks0|Ks1 (16K each) + Vt (16K) = 48K staging; reduction aliases
//  50688B partials + 768B Ll = 51456 total.
// ---------------------------------------------------------------------------
__global__ __launch_bounds__(512, 4)
void attention(const __bf16* __restrict__ Qb, const __bf16* __restrict__ Kb,
               const __bf16* __restrict__ vT, const float* __restrict__ mask,
               float* __restrict__ out)
{
  __shared__ char smem[51456];
  __bf16* Vt = (__bf16*)(smem + 32768);       // [64][128], swizzled+permuted-t

  const int tid  = threadIdx.x;
  const int wave = tid >> 6, lane = tid & 63;
  const int quad = lane >> 4, l16 = lane & 15;
  const int qh = wave >> 2;       // q-half (0..1)
  const int th = wave & 3;        // t-quarter (0..3)
  const int qb = blockIdx.x, h = blockIdx.y;
  const int q0 = qb * 64;
  const int qcol = h * 64;
  const int srow = lane >> 3, sg = lane & 7;
  const int vrow = lane >> 4, vs = lane & 15;

  bf16x8 qf[2][2];
  #pragma unroll
  for (int nt = 0; nt < 2; ++nt)
    #pragma unroll
    for (int kt = 0; kt < 2; ++kt)
      qf[nt][kt] = *reinterpret_cast<const bf16x8*>(
          Qb + (q0 + qh * 32 + nt * 16 + l16) * D + qcol + kt * 32 + quad * 8);

  floatx4 accO[4][2];
  #pragma unroll
  for (int wt = 0; wt < 4; ++wt)
    #pragma unroll
    for (int nt = 0; nt < 2; ++nt) accO[wt][nt] = (floatx4){0.f, 0.f, 0.f, 0.f};
  floatx4 accL[2];
  accL[0] = (floatx4){0.f, 0.f, 0.f, 0.f};
  accL[1] = (floatx4){0.f, 0.f, 0.f, 0.f};
  bf16x8 ones;
  #pragma unroll
  for (int e = 0; e < 8; ++e) ones[e] = (__bf16)1.0f;

  // K tile [128][64]: 512 lanes x 16B = 64 rows/round, 2 rounds.
  auto stageK = [&](int j, __bf16* dst) {
    #pragma unroll
    for (int it = 0; it < 2; ++it) {
      int rbase = it * 64 + wave * 8;
      int t = rbase + srow;
      glds16(Kb + (size_t)(j * 128 + t) * D + qcol + (sg ^ (t & 7)) * 8,
             dst + rbase * 64);
    }
  };
  // V tile [64][128]: 512 lanes x 16B = 32 w-rows/round, 2 rounds.
  auto stageV = [&](int j) {
    #pragma unroll
    for (int it = 0; it < 2; ++it) {
      int wbase = it * 32 + wave * 4;
      int w = wbase + vrow;
      glds16(vT + (size_t)(qcol + w) * S + j * 128 + (vs ^ (w & 7)) * 8,
             Vt + wbase * 128);
    }
  };

  __builtin_amdgcn_sched_barrier(0);
  // prologue: K(0), V(0) in flight
  stageK(0, (__bf16*)smem);
  stageV(0);
  __builtin_amdgcn_sched_barrier(0);

  for (int j = 0; j < 32; ++j) {
    // mask loads for this step (issued before the counted wait)
    floatx4 mv[2];
    #pragma unroll
    for (int mt = 0; mt < 2; ++mt)
      mv[mt] = *reinterpret_cast<const floatx4*>(
          mask + j * 128 + th * 32 + mt * 16 + quad * 4);

    asm volatile("s_waitcnt vmcnt(4)" ::: "memory");   // own K(j) drained
    __builtin_amdgcn_s_barrier();                      // B1: K(j) visible
    __builtin_amdgcn_sched_barrier(0);

    if (j < 31)                                        // prefetch next K
      stageK(j + 1, (__bf16*)(smem + (((j + 1) & 1) << 14)));
    __builtin_amdgcn_sched_barrier(0);

    const __bf16* Kc = (const __bf16*)(smem + ((j & 1) << 14));

    // S^T = K Q^T ; P = exp2(scale*S + mask2) packed directly into pf.
    bf16x8 pf[2];
    #pragma unroll
    for (int mt = 0; mt < 2; ++mt) {
      int trow = th * 32 + mt * 16 + l16;
      bf16x8 kf[2];
      #pragma unroll
      for (int kt = 0; kt < 2; ++kt)
        kf[kt] = *reinterpret_cast<const bf16x8*>(
            &Kc[trow * 64 + ((((kt << 2) | quad) ^ (l16 & 7)) << 3)]);
      floatx4 am;   // (m-1)*10000*log2e ; exactly 0 when m==1
      #pragma unroll
      for (int r = 0; r < 4; ++r)
        am[r] = fmaf(mv[mt][r], 14426.9504f, -14426.9504f);
      #pragma unroll
      for (int nt = 0; nt < 2; ++nt) {
        floatx4 s = (floatx4){0.f, 0.f, 0.f, 0.f};
        #pragma unroll
        for (int kt = 0; kt < 2; ++kt)
          s = __builtin_amdgcn_mfma_f32_16x16x32_bf16(kf[kt], qf[nt][kt], s, 0, 0, 0);
        #pragma unroll
        for (int r = 0; r < 4; ++r)
          pf[nt][mt * 4 + r] = (__bf16)__builtin_amdgcn_exp2f(
              fmaf(s[r], 0.18033688f, am[r]));   // 0.125*log2e
      }
    }

    asm volatile("s_waitcnt vmcnt(2)" ::: "memory");   // V(j) drained; K(j+1) flies
    __builtin_amdgcn_s_barrier();                      // B_mid: V(j) visible
    __builtin_amdgcn_sched_barrier(0);

    // O^T += V^T P^T ; l via ones-MFMA (sums P columns, rows all equal).
    #pragma unroll
    for (int nt = 0; nt < 2; ++nt)
      accL[nt] = __builtin_amdgcn_mfma_f32_16x16x32_bf16(
          ones, pf[nt], accL[nt], 0, 0, 0);
    #pragma unroll
    for (int wt = 0; wt < 4; ++wt) {
      int w = wt * 16 + l16;
      bf16x8 vf = *reinterpret_cast<const bf16x8*>(
          &Vt[w * 128 + (((th * 4 + quad) ^ (w & 7)) << 3)]);
      #pragma unroll
      for (int nt = 0; nt < 2; ++nt)
        accO[wt][nt] = __builtin_amdgcn_mfma_f32_16x16x32_bf16(
            vf, pf[nt], accO[wt][nt], 0, 0, 0);
    }

    __builtin_amdgcn_s_barrier();                      // B2: Vt readers done
    __builtin_amdgcn_sched_barrier(0);
    if (j < 31) stageV(j + 1);                         // prefetch next V
    __builtin_amdgcn_sched_barrier(0);
  }

  // l for q = nt*16+l16 over this wave's 32 t: all 4 acc rows identical.
  float l_lane[2] = {accL[0][0], accL[1][0]};

  // ---- 4-way cross-wave reduction over t-quarters ----
  float* Lo = (float*)smem;              // 6 partials x [64][33] f32 = 50688B
  float* Ll = (float*)(smem + 50688);    // 6 x 32 f32 l partials
  __syncthreads();   // full drain; safe to alias Lo over K/V buffers
  if (th != 0) {
    float* dst = Lo + (qh * 3 + th - 1) * 2112;
    #pragma unroll
    for (int wt = 0; wt < 4; ++wt)
      #pragma unroll
      for (int nt = 0; nt < 2; ++nt)
        #pragma unroll
        for (int r = 0; r < 4; ++r)
          dst[(wt * 16 + quad * 4 + r) * 33 + nt * 16 + l16] = accO[wt][nt][r];
    if (quad == 0) {
      #pragma unroll
      for (int nt = 0; nt < 2; ++nt)
        Ll[(qh * 3 + th - 1) * 32 + nt * 16 + l16] = l_lane[nt];
    }
  }
  __syncthreads();
  if (th == 0) {
    float l_tot[2];
    #pragma unroll
    for (int nt = 0; nt < 2; ++nt) {
      l_tot[nt] = l_lane[nt];
      #pragma unroll
      for (int p = 0; p < 3; ++p)
        l_tot[nt] += Ll[(qh * 3 + p) * 32 + nt * 16 + l16];
    }
    #pragma unroll
    for (int wt = 0; wt < 4; ++wt)
      #pragma unroll
      for (int nt = 0; nt < 2; ++nt) {
        floatx4 o;
        #pragma unroll
        for (int r = 0; r < 4; ++r) {
          float v = accO[wt][nt][r];
          #pragma unroll
          for (int p = 0; p < 3; ++p)
            v += Lo[(qh * 3 + p) * 2112 +
                    (wt * 16 + quad * 4 + r) * 33 + nt * 16 + l16];
          o[r] = v / l_tot[nt];
        }
        int row = q0 + qh * 32 + nt * 16 + l16;
        int col = qcol + wt * 16 + quad * 4;
        *reinterpret_cast<floatx4*>(&out[row * D + col]) = o;
      }
  }
}

} // namespace

extern "C" void kernel_launch(void* const* d_in, const int* in_sizes, int n_in,
                              void* d_out, int out_size, void* d_ws, size_t ws_size,
                              hipStream_t stream) {
  const float *x = nullptr, *mask = nullptr, *Wq = nullptr, *bq = nullptr;
  for (int i = 0; i < n_in; ++i) {
    switch (in_sizes[i]) {
      case 3145728: x    = (const float*)d_in[i]; break;
      case 4096:    mask = (const float*)d_in[i]; break;
      case 1769472: Wq   = (const float*)d_in[i]; break;
      case 2304:    bq   = (const float*)d_in[i]; break;
      default: break;
    }
  }

  __bf16* xb = (__bf16*)d_out;               // bf16 scratch in d_out
  __bf16* WT = xb + (size_t)S * D;
  __bf16* Qb = (__bf16*)d_ws;
  __bf16* Kb = Qb + (size_t)S * D;
  __bf16* vT = Kb + (size_t)S * D;

  convert_all<<<3072 + 432, 256, 0, stream>>>(x, xb, Wq, WT);
  qkv_gemm   <<<dim3(S / 128, N3 / 96), 256, 0, stream>>>(xb, WT, bq, Qb, Kb, vT);
  attention  <<<dim3(S / 64, H), 512, 0, stream>>>(Qb, Kb, vT, mask, (float*)d_out);
}